// Round 13
// baseline (7666.156 us; speedup 1.0000x reference)
//
#include <hip/hip_runtime.h>
#include <cmath>

#define AGENT __HIP_MEMORY_SCOPE_AGENT

// Problem constants
// B=4, S=512, I=H=768, 3H=2304, E=8, K=2, L=2, tokens=2048, assignments=4096

// ---------------- reset ----------------
__global__ void reset_kernel(int* __restrict__ flags, int* __restrict__ counts,
                             float* __restrict__ hbuf0) {
  int i = blockIdx.x * 256 + threadIdx.x;
  if (i < 6208) flags[i] = 0;          // tags[96*32] + slack
  if (i < 16) counts[i] = 0;           // counts[2][8]
  if (i < 3072) hbuf0[i] = 0.f;        // h0 = zeros (layer 0)
}

// ---------------- GEMM: C = op(A @ B^T + bias) ----------------
// A [M x Kd] row-major (lda), B [N x Kd] row-major, C rows scattered if GATHER.
// Tile 128x128x16, 256 threads, 8x8 acc/thread (2x2 blocks of 4x4).
// GI2: remap C store to gi2[t][wg][b][gate][8] layout for the GRU.
template<bool GATHER, bool SHIFT, bool RELU, bool GATE, bool GI2 = false>
__global__ __launch_bounds__(256)
void gemm_nt(const float* __restrict__ A, const float* __restrict__ Bw,
             const float* __restrict__ bias, float* __restrict__ C,
             int M, int N, int Kd, int lda, int ldc,
             const int* __restrict__ list, const int* __restrict__ count,
             const float* __restrict__ gates, long wstride, int bstride)
{
  __shared__ float As[16][132];
  __shared__ float Bs[16][132];
  __shared__ int rowlist[128];

  int e = 0, cnt = M;
  if constexpr (GATHER) { e = blockIdx.z; cnt = count[e]; }
  int mbase = blockIdx.y * 128;
  if (mbase >= cnt) return;
  int nbase = blockIdx.x * 128;
  const float* Bp = Bw + (size_t)e * (size_t)wstride;
  const float* biasp = bias + (size_t)e * (size_t)bstride;

  int tid = threadIdx.x;
  if constexpr (GATHER) {
    if (tid < 128) {
      int r = mbase + tid;
      rowlist[tid] = list[e * 4096 + (r < cnt ? r : cnt - 1)];
    }
    __syncthreads();
  }

  int tx = tid & 15, ty = tid >> 4;

  const float* ap[2];
  const float* bp[2];
  int ldst[2];
#pragma unroll
  for (int i = 0; i < 2; ++i) {
    int v = tid + 256 * i;
    int row = v >> 2, kq = v & 3;
    const float* a0;
    if constexpr (GATHER) {
      int aidx = rowlist[row];
      int sr = SHIFT ? (aidx >> 1) : aidx;
      a0 = A + (size_t)sr * lda;
    } else {
      a0 = A + (size_t)(mbase + row) * lda;
    }
    ap[i] = a0 + kq * 4;
    bp[i] = Bp + (size_t)(nbase + row) * Kd + kq * 4;
    ldst[i] = kq * 4 * 132 + row;
  }

  float acc[8][8];
#pragma unroll
  for (int i = 0; i < 8; ++i)
#pragma unroll
    for (int j = 0; j < 8; ++j) acc[i][j] = 0.f;

  for (int kb = 0; kb < Kd; kb += 16) {
    float4 av[2], bv[2];
#pragma unroll
    for (int i = 0; i < 2; ++i) {
      av[i] = *(const float4*)(ap[i] + kb);
      bv[i] = *(const float4*)(bp[i] + kb);
    }
    if (kb) __syncthreads();
#pragma unroll
    for (int i = 0; i < 2; ++i) {
      float* ad = &As[0][0] + ldst[i];
      ad[0] = av[i].x; ad[132] = av[i].y; ad[264] = av[i].z; ad[396] = av[i].w;
      float* bd = &Bs[0][0] + ldst[i];
      bd[0] = bv[i].x; bd[132] = bv[i].y; bd[264] = bv[i].z; bd[396] = bv[i].w;
    }
    __syncthreads();
#pragma unroll
    for (int kk = 0; kk < 16; ++kk) {
      float a[8], b[8];
      *(float4*)&a[0] = *(const float4*)&As[kk][ty * 4];
      *(float4*)&a[4] = *(const float4*)&As[kk][ty * 4 + 64];
      *(float4*)&b[0] = *(const float4*)&Bs[kk][tx * 4];
      *(float4*)&b[4] = *(const float4*)&Bs[kk][tx * 4 + 64];
#pragma unroll
      for (int i = 0; i < 8; ++i)
#pragma unroll
        for (int j = 0; j < 8; ++j)
          acc[i][j] = fmaf(a[i], b[j], acc[i][j]);
    }
  }

#pragma unroll
  for (int i = 0; i < 8; ++i) {
    int lrow = ty * 4 + (i & 3) + ((i >> 2) << 6);
    int grow = mbase + lrow;
    bool ok = true;
    int orow = grow;
    float gs = 1.f;
    if constexpr (GATHER) {
      ok = (grow < cnt);
      int aidx = rowlist[lrow];
      orow = aidx;
      if constexpr (GATE) gs = gates[aidx];
    }
    if (ok) {
#pragma unroll
      for (int q = 0; q < 2; ++q) {
        int col = nbase + tx * 4 + (q << 6);
        float4 bb = *(const float4*)&biasp[col];
        float r0 = acc[i][q * 4 + 0] + bb.x;
        float r1 = acc[i][q * 4 + 1] + bb.y;
        float r2 = acc[i][q * 4 + 2] + bb.z;
        float r3 = acc[i][q * 4 + 3] + bb.w;
        if constexpr (RELU) {
          r0 = fmaxf(r0, 0.f); r1 = fmaxf(r1, 0.f);
          r2 = fmaxf(r2, 0.f); r3 = fmaxf(r3, 0.f);
        }
        if constexpr (GATE) { r0 *= gs; r1 *= gs; r2 *= gs; r3 *= gs; }
        float4 st = make_float4(r0, r1, r2, r3);
        if constexpr (GI2) {
          // gi2[t][wg][b][gate][8]; col%8 in {0,4} so float4 stays in-octet
          int t = grow & 511, bb2 = grow >> 9;
          int gate = col / 768, jj = col - gate * 768;
          int wg2 = jj >> 3, o = jj & 7;
          float* dst = C + ((((size_t)t * 96 + wg2) * 4 + bb2) * 3 + gate) * 8 + o;
          *(float4*)dst = st;
        } else {
          *(float4*)&C[(size_t)orow * ldc + col] = st;
        }
      }
    }
  }
}

// ---------------- GRU persistent kernel ----------------
// 96 WGs x 512 threads; wave w owns output column j = wg*8+wave.
// Tag-gated producer/consumer (round-8 proven structure):
// Producer: store 32 h floats (coherent) -> vmcnt(0) -> syncthreads ->
//           tags[wg] = step+1 (own cache line, zero contention).
// Consumer: wave0 polls all 96 tags >= step -> syncthreads -> WG bulk-loads
//           h [4x768] coherent into LDS -> compute.
// This round: h_seq writes SHARDED (each WG writes only its 128B slice from
// already-staged registers) so the producer vmcnt(0) queue holds only the 4
// scalar h stores; poll sleep lengthened to cut LLC poll traffic 4x.
__global__ __launch_bounds__(512)
void gru_kernel(const float* __restrict__ gi2, float* __restrict__ h_seq,
                float* __restrict__ hbuf, const float* __restrict__ Whh,
                const float* __restrict__ bhh,
                int* __restrict__ tags, int stepBase)
{
  const int H = 768, S = 512;
  __shared__ float hs[3072];
  int wg = blockIdx.x;           // 0..95
  int tid = threadIdx.x;         // 0..511
  int wave = tid >> 6;           // 0..7
  int lane = tid & 63;
  int j = wg * 8 + wave;

  // W[g][q*4+k] = Whh[g*H+j][q*256 + lane*4 + k]
  float W[3][12];
#pragma unroll
  for (int g = 0; g < 3; ++g) {
    const float* wp = Whh + (size_t)(g * H + j) * H + lane * 4;
    *(float4*)&W[g][0] = *(const float4*)(wp);
    *(float4*)&W[g][4] = *(const float4*)(wp + 256);
    *(float4*)&W[g][8] = *(const float4*)(wp + 512);
  }
  float bh_r = bhh[j], bh_z = bhh[H + j], bh_n = bhh[2 * H + j];

  float h_own = 0.f;
  if (lane < 4)
    h_own = __hip_atomic_load(&hbuf[(stepBase & 1) * 3072 + lane * H + j],
                              __ATOMIC_RELAXED, AGENT);

  for (int tl = 0; tl < S; ++tl) {
    int g = stepBase + tl;
    const float* hb = hbuf + (g & 1) * 3072;
    float* hw = hbuf + ((g + 1) & 1) * 3072;

    // gi2 prefetch: lane i<12 loads element [b=i&3][gate=i>>2] for this wave's j
    float gv = 0.f;
    if (lane < 12)
      gv = gi2[(((size_t)tl * 96 + wg) * 12 + ((lane & 3) * 3 + (lane >> 2))) * 8 + wave];

    // ---- tag poll: wave0 waits until all 96 producers reached step g ----
    if (wave == 0) {
      for (;;) {
        int v1 = __hip_atomic_load(&tags[lane * 32], __ATOMIC_RELAXED, AGENT);
        int v2 = (lane < 32)
            ? __hip_atomic_load(&tags[(64 + lane) * 32], __ATOMIC_RELAXED, AGENT)
            : 0x7fffffff;
        if (__all(v1 >= g && v2 >= g)) break;
        __builtin_amdgcn_s_sleep(4);
      }
    }
    __syncthreads();

    // ---- stage h into LDS: coalesced coherent float4 loads ----
    float4 a, b4v;
    asm volatile("global_load_dwordx4 %0, %1, off sc0 sc1"
                 : "=v"(a) : "v"(hb + tid * 4) : "memory");
    if (tid < 256)   // wave-uniform (waves 0..3)
      asm volatile("global_load_dwordx4 %0, %1, off sc0 sc1"
                   : "=v"(b4v) : "v"(hb + 2048 + tid * 4) : "memory");
    asm volatile("s_waitcnt vmcnt(0)" ::: "memory");
    __builtin_amdgcn_sched_barrier(0);
    *(float4*)&hs[tid * 4] = a;
    if (tid < 256) *(float4*)&hs[2048 + tid * 4] = b4v;
    __syncthreads();

    // ---- SHARDED h_seq write of h[tl-1]: WG w writes floats [w*32,w*32+32)
    // (128 B, from already-staged registers; drains during compute) ----
    if (tl >= 1) {
      if (wg < 64) {
        int rel = tid - wg * 8;
        if (rel >= 0 && rel < 8) {
          int i0 = tid * 4, bb = i0 / 768, d = i0 - bb * 768;
          *(float4*)&h_seq[((size_t)bb * S + (tl - 1)) * H + d] = a;
        }
      } else {
        int rel = tid - (wg - 64) * 8;
        if (rel >= 0 && rel < 8) {
          int i1 = 2048 + tid * 4, bb1 = i1 / 768, d1 = i1 - bb1 * 768;
          *(float4*)&h_seq[((size_t)bb1 * S + (tl - 1)) * H + d1] = b4v;
        }
      }
    }

    // ---- fragments from LDS ----
    float hseg[4][12];
#pragma unroll
    for (int b4 = 0; b4 < 4; ++b4) {
      *(float4*)&hseg[b4][0] = *(const float4*)&hs[b4 * 768 + lane * 4];
      *(float4*)&hseg[b4][4] = *(const float4*)&hs[b4 * 768 + 256 + lane * 4];
      *(float4*)&hseg[b4][8] = *(const float4*)&hs[b4 * 768 + 512 + lane * 4];
    }

    float acc[3][4];
#pragma unroll
    for (int gg = 0; gg < 3; ++gg)
#pragma unroll
      for (int b4 = 0; b4 < 4; ++b4) {
        float s = 0.f;
#pragma unroll
        for (int i = 0; i < 12; ++i) s = fmaf(W[gg][i], hseg[b4][i], s);
        acc[gg][b4] = s;
      }
#pragma unroll
    for (int gg = 0; gg < 3; ++gg)
#pragma unroll
      for (int b4 = 0; b4 < 4; ++b4) {
        float v = acc[gg][b4];
#pragma unroll
        for (int m = 32; m >= 1; m >>= 1) v += __shfl_xor(v, m);
        acc[gg][b4] = v;
      }

    // gi distribute (all lanes participate in shfl)
    float gi_r = __shfl(gv, (lane & 3));
    float gi_z = __shfl(gv, 4 + (lane & 3));
    float gi_n = __shfl(gv, 8 + (lane & 3));

    if (lane < 4) {
      float ar = acc[0][0], az = acc[1][0], an = acc[2][0];
      if (lane == 1) { ar = acc[0][1]; az = acc[1][1]; an = acc[2][1]; }
      if (lane == 2) { ar = acc[0][2]; az = acc[1][2]; an = acc[2][2]; }
      if (lane == 3) { ar = acc[0][3]; az = acc[1][3]; an = acc[2][3]; }
      float r = 1.f / (1.f + expf(-(gi_r + ar + bh_r)));
      float z = 1.f / (1.f + expf(-(gi_z + az + bh_z)));
      float n = tanhf(gi_n + r * (an + bh_n));
      float hn = (1.f - z) * n + z * h_own;
      h_own = hn;
      __hip_atomic_store(&hw[lane * H + j], hn, __ATOMIC_RELAXED, AGENT);
    }

    // ---- publish: own h stores acked -> all waves joined -> tag ----
    asm volatile("s_waitcnt vmcnt(0)" ::: "memory");
    __syncthreads();
    if (tid == 0)
      __hip_atomic_store(&tags[wg * 32], g + 1, __ATOMIC_RELAXED, AGENT);
  }

  // epilogue: each WG writes its own slice of h_seq[S-1] from registers
  if (lane < 4)
    h_seq[((size_t)lane * S + (S - 1)) * H + j] = h_own;
}

// ---------------- router + top-2 + gates + expert lists ----------------
__global__ __launch_bounds__(64)
void router_kernel(const float* __restrict__ h_seq, const float* __restrict__ rW,
                   const float* __restrict__ rb, int* __restrict__ counts,
                   int* __restrict__ lists, float* __restrict__ gates)
{
  int t = blockIdx.x;       // token 0..2047
  int lane = threadIdx.x;   // 0..63
  const float* hp = h_seq + (size_t)t * 768 + lane * 12;
  float h[12];
  *(float4*)&h[0] = *(const float4*)(hp);
  *(float4*)&h[4] = *(const float4*)(hp + 4);
  *(float4*)&h[8] = *(const float4*)(hp + 8);

  float lg[8];
#pragma unroll
  for (int e = 0; e < 8; ++e) {
    const float* wp = rW + e * 768 + lane * 12;
    float s = 0.f;
#pragma unroll
    for (int i = 0; i < 12; ++i) s = fmaf(h[i], wp[i], s);
#pragma unroll
    for (int m = 32; m >= 1; m >>= 1) s += __shfl_xor(s, m);
    lg[e] = s + rb[e];
  }
  if (lane == 0) {
    float v1 = lg[0]; int e1 = 0;
#pragma unroll
    for (int e = 1; e < 8; ++e) {
      if (lg[e] > v1) { v1 = lg[e]; e1 = e; }
    }
    float v2 = -INFINITY; int es = 0;
#pragma unroll
    for (int e = 0; e < 8; ++e) {
      if (e != e1 && lg[e] > v2) { v2 = lg[e]; es = e; }
    }
    float ed = expf(v2 - v1);
    float g1 = 1.f / (1.f + ed);
    float g2 = ed / (1.f + ed);
    int a0 = t * 2, a1 = t * 2 + 1;
    gates[a0] = g1;
    gates[a1] = g2;
    int p = atomicAdd(&counts[e1], 1);
    lists[e1 * 4096 + p] = a0;
    p = atomicAdd(&counts[es], 1);
    lists[es * 4096 + p] = a1;
  }
}

// ---------------- combine: x_next[t] = ybuf[2t] + ybuf[2t+1] ----------------
__global__ __launch_bounds__(256)
void combine_kernel(const float* __restrict__ ybuf, float* __restrict__ out)
{
  int i = blockIdx.x * 256 + threadIdx.x;     // one float4 each
  int fi = i * 4;                              // < 2048*768
  int t = fi / 768;
  int d = fi % 768;
  float4 y0 = *(const float4*)&ybuf[(size_t)(2 * t) * 768 + d];
  float4 y1 = *(const float4*)&ybuf[(size_t)(2 * t + 1) * 768 + d];
  float4 r = make_float4(y0.x + y1.x, y0.y + y1.y, y0.z + y1.z, y0.w + y1.w);
  *(float4*)&out[fi] = r;
}

// ---------------- host ----------------
extern "C" void kernel_launch(void* const* d_in, const int* in_sizes, int n_in,
                              void* d_out, int out_size, void* d_ws, size_t ws_size,
                              hipStream_t stream) {
  (void)in_sizes; (void)n_in; (void)out_size; (void)ws_size;
  const float* x      = (const float*)d_in[0];
  const float* proj_W = (const float*)d_in[1];
  const float* proj_b = (const float*)d_in[2];
  const float* Wih    = (const float*)d_in[3];
  const float* Whh    = (const float*)d_in[4];
  const float* bih    = (const float*)d_in[5];
  const float* bhh    = (const float*)d_in[6];
  const float* rW     = (const float*)d_in[7];
  const float* rb     = (const float*)d_in[8];
  const float* eW1    = (const float*)d_in[9];
  const float* eb1    = (const float*)d_in[10];
  const float* eW2    = (const float*)d_in[11];
  const float* eb2    = (const float*)d_in[12];
  float* out = (float*)d_out;

  // workspace layout (floats)
  float* f = (float*)d_ws;
  float* h_in  = f;                    // 2048*768
  float* gi2   = h_in + 1572864;       // 512*96*4*3*8 = 4718592
  float* h_seq = gi2 + 4718592;        // 2048*768
  float* x_buf = h_seq + 1572864;      // 2048*768
  float* H1    = x_buf + 1572864;      // 4096*3072
  float* ybuf  = H1 + 12582912;        // 4096*768
  float* hbuf  = ybuf + 3145728;       // 2*3072
  float* gates = hbuf + 6144;          // 4096
  int* ints    = (int*)(gates + 4096);
  int* counts  = ints;                 // 16
  int* lists   = ints + 16;            // 8*4096
  int* tags    = ints + 16 + 32768;    // 96*32 tags

  reset_kernel<<<25, 256, 0, stream>>>(tags, counts, hbuf);

  for (int l = 0; l < 2; ++l) {
    const float* xin = l ? x_buf : x;

    dim3 g1(6, 16);
    gemm_nt<false, false, false, false><<<g1, 256, 0, stream>>>(
        xin, proj_W + (size_t)l * 768 * 768, proj_b + l * 768, h_in,
        2048, 768, 768, 768, 768, nullptr, nullptr, nullptr, 0, 0);

    dim3 g2(18, 16);
    gemm_nt<false, false, false, false, true><<<g2, 256, 0, stream>>>(
        h_in, Wih, bih, gi2,
        2048, 2304, 768, 768, 0, nullptr, nullptr, nullptr, 0, 0);

    gru_kernel<<<96, 512, 0, stream>>>(gi2, h_seq, hbuf, Whh, bhh,
                                       tags, l * 512);

    router_kernel<<<2048, 64, 0, stream>>>(h_seq, rW + (size_t)l * 8 * 768,
                                           rb + l * 8, counts + l * 8, lists, gates);

    dim3 ga(24, 32, 8);
    gemm_nt<true, true, true, false><<<ga, 256, 0, stream>>>(
        xin, eW1 + (size_t)l * 8 * 3072 * 768, eb1 + (size_t)l * 8 * 3072, H1,
        4096, 3072, 768, 768, 3072, lists, counts + l * 8, nullptr,
        (long)3072 * 768, 3072);

    dim3 gb(6, 32, 8);
    gemm_nt<true, false, false, true><<<gb, 256, 0, stream>>>(
        H1, eW2 + (size_t)l * 8 * 768 * 3072, eb2 + (size_t)l * 8 * 768, ybuf,
        4096, 768, 3072, 3072, 768, lists, counts + l * 8, gates,
        (long)768 * 3072, 768);

    combine_kernel<<<1536, 256, 0, stream>>>(ybuf, l ? out : x_buf);
  }
}

// Round 14
// 6070.390 us; speedup vs baseline: 1.2629x; 1.2629x over previous
//
#include <hip/hip_runtime.h>
#include <cmath>

#define AGENT __HIP_MEMORY_SCOPE_AGENT

// Problem constants
// B=4, S=512, I=H=768, 3H=2304, E=8, K=2, L=2, tokens=2048, assignments=4096

typedef __attribute__((ext_vector_type(8))) short short8;
typedef __attribute__((ext_vector_type(4))) float f32x4;

// ---------------- reset ----------------
__global__ void reset_kernel(int* __restrict__ flags, int* __restrict__ counts,
                             float* __restrict__ hbuf0) {
  int i = blockIdx.x * 256 + threadIdx.x;
  if (i < 6208) flags[i] = 0;          // tags[96*32] + slack
  if (i < 16) counts[i] = 0;           // counts[2][8]
  if (i < 3072) hbuf0[i] = 0.f;        // h0 = zeros (layer 0)
}

// ---------------- split fp32 -> bf16 hi/lo planes ----------------
__global__ __launch_bounds__(256)
void split_kernel(const float* __restrict__ in, short* __restrict__ hi,
                  short* __restrict__ lo, int n4) {
  int i = blockIdx.x * 256 + threadIdx.x;
  if (i >= n4) return;
  float4 v = ((const float4*)in)[i];
  unsigned ua = __float_as_uint(v.x), ub = __float_as_uint(v.y);
  unsigned uc = __float_as_uint(v.z), ud = __float_as_uint(v.w);
  unsigned ha = ua & 0xFFFF0000u, hb = ub & 0xFFFF0000u;
  unsigned hc = uc & 0xFFFF0000u, hd = ud & 0xFFFF0000u;
  unsigned hp0 = (ua >> 16) | hb;
  unsigned hp1 = (uc >> 16) | hd;
  float la = v.x - __uint_as_float(ha), lb = v.y - __uint_as_float(hb);
  float lc = v.z - __uint_as_float(hc), ld = v.w - __uint_as_float(hd);
  unsigned lp0 = (__float_as_uint(la) >> 16) | (__float_as_uint(lb) & 0xFFFF0000u);
  unsigned lp1 = (__float_as_uint(lc) >> 16) | (__float_as_uint(ld) & 0xFFFF0000u);
  ((uint2*)hi)[i] = make_uint2(hp0, hp1);
  ((uint2*)lo)[i] = make_uint2(lp0, lp1);
}

// ---------------- dense fp32 GEMM (proj / gi) ----------------
// C = A @ B^T + bias. Tile 128x128x16, 256 threads, 8x8 acc/thread.
// GI2: remap C store to gi2[t][wg][b][gate][8] layout for the GRU.
template<bool GI2>
__global__ __launch_bounds__(256)
void gemm_nt(const float* __restrict__ A, const float* __restrict__ Bw,
             const float* __restrict__ bias, float* __restrict__ C,
             int Kd, int lda, int ldc)
{
  __shared__ float As[16][132];
  __shared__ float Bs[16][132];

  int mbase = blockIdx.y * 128;
  int nbase = blockIdx.x * 128;
  int tid = threadIdx.x;
  int tx = tid & 15, ty = tid >> 4;

  const float* ap[2];
  const float* bp[2];
  int ldst[2];
#pragma unroll
  for (int i = 0; i < 2; ++i) {
    int v = tid + 256 * i;
    int row = v >> 2, kq = v & 3;
    ap[i] = A + (size_t)(mbase + row) * lda + kq * 4;
    bp[i] = Bw + (size_t)(nbase + row) * Kd + kq * 4;
    ldst[i] = kq * 4 * 132 + row;
  }

  float acc[8][8];
#pragma unroll
  for (int i = 0; i < 8; ++i)
#pragma unroll
    for (int j = 0; j < 8; ++j) acc[i][j] = 0.f;

  for (int kb = 0; kb < Kd; kb += 16) {
    float4 av[2], bv[2];
#pragma unroll
    for (int i = 0; i < 2; ++i) {
      av[i] = *(const float4*)(ap[i] + kb);
      bv[i] = *(const float4*)(bp[i] + kb);
    }
    if (kb) __syncthreads();
#pragma unroll
    for (int i = 0; i < 2; ++i) {
      float* ad = &As[0][0] + ldst[i];
      ad[0] = av[i].x; ad[132] = av[i].y; ad[264] = av[i].z; ad[396] = av[i].w;
      float* bd = &Bs[0][0] + ldst[i];
      bd[0] = bv[i].x; bd[132] = bv[i].y; bd[264] = bv[i].z; bd[396] = bv[i].w;
    }
    __syncthreads();
#pragma unroll
    for (int kk = 0; kk < 16; ++kk) {
      float a[8], b[8];
      *(float4*)&a[0] = *(const float4*)&As[kk][ty * 4];
      *(float4*)&a[4] = *(const float4*)&As[kk][ty * 4 + 64];
      *(float4*)&b[0] = *(const float4*)&Bs[kk][tx * 4];
      *(float4*)&b[4] = *(const float4*)&Bs[kk][tx * 4 + 64];
#pragma unroll
      for (int i = 0; i < 8; ++i)
#pragma unroll
        for (int j = 0; j < 8; ++j)
          acc[i][j] = fmaf(a[i], b[j], acc[i][j]);
    }
  }

#pragma unroll
  for (int i = 0; i < 8; ++i) {
    int lrow = ty * 4 + (i & 3) + ((i >> 2) << 6);
    int grow = mbase + lrow;
#pragma unroll
    for (int q = 0; q < 2; ++q) {
      int col = nbase + tx * 4 + (q << 6);
      float4 bb = *(const float4*)&bias[col];
      float4 st = make_float4(acc[i][q * 4 + 0] + bb.x, acc[i][q * 4 + 1] + bb.y,
                              acc[i][q * 4 + 2] + bb.z, acc[i][q * 4 + 3] + bb.w);
      if constexpr (GI2) {
        int t = grow & 511, bb2 = grow >> 9;
        int gate = col / 768, jj = col - gate * 768;
        int wg2 = jj >> 3, o = jj & 7;
        float* dst = C + ((((size_t)t * 96 + wg2) * 4 + bb2) * 3 + gate) * 8 + o;
        *(float4*)dst = st;
      } else {
        *(float4*)&C[(size_t)grow * ldc + col] = st;
      }
    }
  }
}

// ---------------- split-bf16 MFMA expert GEMM ----------------
// C[aidx][:] = op( A[gather] @ B^T + bias ).
// A pre-split into bf16 hi/lo short planes; B fp32 split during staging.
// A@B ~= Ah@Bh + Ah@Bl + Al@Bh  (error ~2^-16 relative).
// Tile 128x128, BK=32, 4 waves x (4x4) mfma_f32_16x16x32_bf16 fragments.
// C/D layout (m89-verified): col=lane&15, row=(lane>>4)*4+reg.
template<bool SHIFT, bool RELU, bool GATE, bool OUTSPLIT>
__global__ __launch_bounds__(256)
void gemm_mfma(const short* __restrict__ Ah_g, const short* __restrict__ Al_g,
               const float* __restrict__ Bw, const float* __restrict__ bias,
               float* __restrict__ C, short* __restrict__ Ch,
               short* __restrict__ Cl, int Kd, int lda, int ldc,
               const int* __restrict__ list, const int* __restrict__ count,
               const float* __restrict__ gates, long wstride, int bstride)
{
  __shared__ __align__(16) short Ah[128][40];   // +8 pad: 80B row = 2-way banks
  __shared__ __align__(16) short Al[128][40];
  __shared__ __align__(16) short Bh[128][40];
  __shared__ __align__(16) short Bl[128][40];
  __shared__ int rowlist[128];

  int e = blockIdx.z;
  int cnt = count[e];
  int mbase = blockIdx.y * 128;
  if (mbase >= cnt) return;
  int nbase = blockIdx.x * 128;
  const float* Bp = Bw + (size_t)e * (size_t)wstride;
  const float* biasp = bias + (size_t)e * (size_t)bstride;

  int tid = threadIdx.x;
  if (tid < 128) {
    int r = mbase + tid;
    rowlist[tid] = list[e * 4096 + (r < cnt ? r : cnt - 1)];
  }
  __syncthreads();

  int arow = tid >> 1, ahalf = tid & 1;      // 2 threads/row, 16 elems each
  int aidx0 = rowlist[arow];
  int sr = SHIFT ? (aidx0 >> 1) : aidx0;
  const short* aph = Ah_g + (size_t)sr * lda + ahalf * 16;
  const short* apl = Al_g + (size_t)sr * lda + ahalf * 16;
  const float* bp = Bp + (size_t)(nbase + arow) * Kd + ahalf * 16;

  int wave = tid >> 6, lane = tid & 63;
  int wr = (wave >> 1) * 64, wc = (wave & 1) * 64;
  int fr = lane & 15, fo = (lane >> 4) * 8;

  f32x4 acc[4][4];
#pragma unroll
  for (int i = 0; i < 4; ++i)
#pragma unroll
    for (int j = 0; j < 4; ++j) acc[i][j] = f32x4{0.f, 0.f, 0.f, 0.f};

  for (int kb = 0; kb < Kd; kb += 32) {
    uint4 a_h0 = *(const uint4*)(aph + kb);
    uint4 a_h1 = *(const uint4*)(aph + kb + 8);
    uint4 a_l0 = *(const uint4*)(apl + kb);
    uint4 a_l1 = *(const uint4*)(apl + kb + 8);
    float4 b0 = *(const float4*)(bp + kb);
    float4 b1 = *(const float4*)(bp + kb + 4);
    float4 b2 = *(const float4*)(bp + kb + 8);
    float4 b3 = *(const float4*)(bp + kb + 12);
    if (kb) __syncthreads();
    *(uint4*)&Ah[arow][ahalf * 16] = a_h0;
    *(uint4*)&Ah[arow][ahalf * 16 + 8] = a_h1;
    *(uint4*)&Al[arow][ahalf * 16] = a_l0;
    *(uint4*)&Al[arow][ahalf * 16 + 8] = a_l1;
    unsigned hp[8], lp[8];
    const float4 bbv[4] = {b0, b1, b2, b3};
#pragma unroll
    for (int q = 0; q < 4; ++q) {
      unsigned ua = __float_as_uint(bbv[q].x), ub = __float_as_uint(bbv[q].y);
      unsigned uc = __float_as_uint(bbv[q].z), ud = __float_as_uint(bbv[q].w);
      unsigned ha = ua & 0xFFFF0000u, hb = ub & 0xFFFF0000u;
      unsigned hc = uc & 0xFFFF0000u, hd = ud & 0xFFFF0000u;
      hp[q * 2] = (ua >> 16) | hb;
      hp[q * 2 + 1] = (uc >> 16) | hd;
      float la = bbv[q].x - __uint_as_float(ha);
      float lb = bbv[q].y - __uint_as_float(hb);
      float lc = bbv[q].z - __uint_as_float(hc);
      float ld = bbv[q].w - __uint_as_float(hd);
      lp[q * 2] = (__float_as_uint(la) >> 16) | (__float_as_uint(lb) & 0xFFFF0000u);
      lp[q * 2 + 1] = (__float_as_uint(lc) >> 16) | (__float_as_uint(ld) & 0xFFFF0000u);
    }
    *(uint4*)&Bh[arow][ahalf * 16] = make_uint4(hp[0], hp[1], hp[2], hp[3]);
    *(uint4*)&Bh[arow][ahalf * 16 + 8] = make_uint4(hp[4], hp[5], hp[6], hp[7]);
    *(uint4*)&Bl[arow][ahalf * 16] = make_uint4(lp[0], lp[1], lp[2], lp[3]);
    *(uint4*)&Bl[arow][ahalf * 16 + 8] = make_uint4(lp[4], lp[5], lp[6], lp[7]);
    __syncthreads();

    short8 fah[4], fal[4], fbh[4], fbl[4];
#pragma unroll
    for (int mt = 0; mt < 4; ++mt) {
      fah[mt] = *(const short8*)&Ah[wr + mt * 16 + fr][fo];
      fal[mt] = *(const short8*)&Al[wr + mt * 16 + fr][fo];
    }
#pragma unroll
    for (int nt = 0; nt < 4; ++nt) {
      fbh[nt] = *(const short8*)&Bh[wc + nt * 16 + fr][fo];
      fbl[nt] = *(const short8*)&Bl[wc + nt * 16 + fr][fo];
    }
#pragma unroll
    for (int mt = 0; mt < 4; ++mt)
#pragma unroll
      for (int nt = 0; nt < 4; ++nt) {
        acc[mt][nt] = __builtin_amdgcn_mfma_f32_16x16x32_bf16(fah[mt], fbh[nt], acc[mt][nt], 0, 0, 0);
        acc[mt][nt] = __builtin_amdgcn_mfma_f32_16x16x32_bf16(fah[mt], fbl[nt], acc[mt][nt], 0, 0, 0);
        acc[mt][nt] = __builtin_amdgcn_mfma_f32_16x16x32_bf16(fal[mt], fbh[nt], acc[mt][nt], 0, 0, 0);
      }
  }

  int crow = (lane >> 4) * 4;
#pragma unroll
  for (int mt = 0; mt < 4; ++mt) {
#pragma unroll
    for (int q = 0; q < 4; ++q) {
      int lrow = wr + mt * 16 + crow + q;
      int grow = mbase + lrow;
      if (grow < cnt) {
        int aidx = rowlist[lrow];
#pragma unroll
        for (int nt = 0; nt < 4; ++nt) {
          int col = nbase + wc + nt * 16 + fr;
          float v = acc[mt][nt][q] + biasp[col];
          if (RELU) v = fmaxf(v, 0.f);
          if (GATE) v *= gates[aidx];
          if (OUTSPLIT) {
            unsigned u = __float_as_uint(v);
            unsigned h = u & 0xFFFF0000u;
            Ch[(size_t)aidx * ldc + col] = (short)(u >> 16);
            float l2 = v - __uint_as_float(h);
            Cl[(size_t)aidx * ldc + col] = (short)(__float_as_uint(l2) >> 16);
          } else {
            C[(size_t)aidx * ldc + col] = v;
          }
        }
      }
    }
  }
}

// ---------------- GRU persistent kernel (round-13 proven) ----------------
__global__ __launch_bounds__(512)
void gru_kernel(const float* __restrict__ gi2, float* __restrict__ h_seq,
                float* __restrict__ hbuf, const float* __restrict__ Whh,
                const float* __restrict__ bhh,
                int* __restrict__ tags, int stepBase)
{
  const int H = 768, S = 512;
  __shared__ float hs[3072];
  int wg = blockIdx.x;
  int tid = threadIdx.x;
  int wave = tid >> 6;
  int lane = tid & 63;
  int j = wg * 8 + wave;

  float W[3][12];
#pragma unroll
  for (int g = 0; g < 3; ++g) {
    const float* wp = Whh + (size_t)(g * H + j) * H + lane * 4;
    *(float4*)&W[g][0] = *(const float4*)(wp);
    *(float4*)&W[g][4] = *(const float4*)(wp + 256);
    *(float4*)&W[g][8] = *(const float4*)(wp + 512);
  }
  float bh_r = bhh[j], bh_z = bhh[H + j], bh_n = bhh[2 * H + j];

  float h_own = 0.f;
  if (lane < 4)
    h_own = __hip_atomic_load(&hbuf[(stepBase & 1) * 3072 + lane * H + j],
                              __ATOMIC_RELAXED, AGENT);

  for (int tl = 0; tl < S; ++tl) {
    int g = stepBase + tl;
    const float* hb = hbuf + (g & 1) * 3072;
    float* hw = hbuf + ((g + 1) & 1) * 3072;

    float gv = 0.f;
    if (lane < 12)
      gv = gi2[(((size_t)tl * 96 + wg) * 12 + ((lane & 3) * 3 + (lane >> 2))) * 8 + wave];

    if (wave == 0) {
      for (;;) {
        int v1 = __hip_atomic_load(&tags[lane * 32], __ATOMIC_RELAXED, AGENT);
        int v2 = (lane < 32)
            ? __hip_atomic_load(&tags[(64 + lane) * 32], __ATOMIC_RELAXED, AGENT)
            : 0x7fffffff;
        if (__all(v1 >= g && v2 >= g)) break;
        __builtin_amdgcn_s_sleep(4);
      }
    }
    __syncthreads();

    float4 a, b4v;
    asm volatile("global_load_dwordx4 %0, %1, off sc0 sc1"
                 : "=v"(a) : "v"(hb + tid * 4) : "memory");
    if (tid < 256)
      asm volatile("global_load_dwordx4 %0, %1, off sc0 sc1"
                   : "=v"(b4v) : "v"(hb + 2048 + tid * 4) : "memory");
    asm volatile("s_waitcnt vmcnt(0)" ::: "memory");
    __builtin_amdgcn_sched_barrier(0);
    *(float4*)&hs[tid * 4] = a;
    if (tid < 256) *(float4*)&hs[2048 + tid * 4] = b4v;
    __syncthreads();

    if (tl >= 1) {
      if (wg < 64) {
        int rel = tid - wg * 8;
        if (rel >= 0 && rel < 8) {
          int i0 = tid * 4, bb = i0 / 768, d = i0 - bb * 768;
          *(float4*)&h_seq[((size_t)bb * S + (tl - 1)) * H + d] = a;
        }
      } else {
        int rel = tid - (wg - 64) * 8;
        if (rel >= 0 && rel < 8) {
          int i1 = 2048 + tid * 4, bb1 = i1 / 768, d1 = i1 - bb1 * 768;
          *(float4*)&h_seq[((size_t)bb1 * S + (tl - 1)) * H + d1] = b4v;
        }
      }
    }

    float hseg[4][12];
#pragma unroll
    for (int b4 = 0; b4 < 4; ++b4) {
      *(float4*)&hseg[b4][0] = *(const float4*)&hs[b4 * 768 + lane * 4];
      *(float4*)&hseg[b4][4] = *(const float4*)&hs[b4 * 768 + 256 + lane * 4];
      *(float4*)&hseg[b4][8] = *(const float4*)&hs[b4 * 768 + 512 + lane * 4];
    }

    float acc[3][4];
#pragma unroll
    for (int gg = 0; gg < 3; ++gg)
#pragma unroll
      for (int b4 = 0; b4 < 4; ++b4) {
        float s = 0.f;
#pragma unroll
        for (int i = 0; i < 12; ++i) s = fmaf(W[gg][i], hseg[b4][i], s);
        acc[gg][b4] = s;
      }
#pragma unroll
    for (int gg = 0; gg < 3; ++gg)
#pragma unroll
      for (int b4 = 0; b4 < 4; ++b4) {
        float v = acc[gg][b4];
#pragma unroll
        for (int m = 32; m >= 1; m >>= 1) v += __shfl_xor(v, m);
        acc[gg][b4] = v;
      }

    float gi_r = __shfl(gv, (lane & 3));
    float gi_z = __shfl(gv, 4 + (lane & 3));
    float gi_n = __shfl(gv, 8 + (lane & 3));

    if (lane < 4) {
      float ar = acc[0][0], az = acc[1][0], an = acc[2][0];
      if (lane == 1) { ar = acc[0][1]; az = acc[1][1]; an = acc[2][1]; }
      if (lane == 2) { ar = acc[0][2]; az = acc[1][2]; an = acc[2][2]; }
      if (lane == 3) { ar = acc[0][3]; az = acc[1][3]; an = acc[2][3]; }
      float r = 1.f / (1.f + expf(-(gi_r + ar + bh_r)));
      float z = 1.f / (1.f + expf(-(gi_z + az + bh_z)));
      float n = tanhf(gi_n + r * (an + bh_n));
      float hn = (1.f - z) * n + z * h_own;
      h_own = hn;
      __hip_atomic_store(&hw[lane * H + j], hn, __ATOMIC_RELAXED, AGENT);
    }

    asm volatile("s_waitcnt vmcnt(0)" ::: "memory");
    __syncthreads();
    if (tid == 0)
      __hip_atomic_store(&tags[wg * 32], g + 1, __ATOMIC_RELAXED, AGENT);
  }

  if (lane < 4)
    h_seq[((size_t)lane * S + (S - 1)) * H + j] = h_own;
}

// ---------------- router + top-2 + gates + expert lists ----------------
__global__ __launch_bounds__(64)
void router_kernel(const float* __restrict__ h_seq, const float* __restrict__ rW,
                   const float* __restrict__ rb, int* __restrict__ counts,
                   int* __restrict__ lists, float* __restrict__ gates)
{
  int t = blockIdx.x;
  int lane = threadIdx.x;
  const float* hp = h_seq + (size_t)t * 768 + lane * 12;
  float h[12];
  *(float4*)&h[0] = *(const float4*)(hp);
  *(float4*)&h[4] = *(const float4*)(hp + 4);
  *(float4*)&h[8] = *(const float4*)(hp + 8);

  float lg[8];
#pragma unroll
  for (int e = 0; e < 8; ++e) {
    const float* wp = rW + e * 768 + lane * 12;
    float s = 0.f;
#pragma unroll
    for (int i = 0; i < 12; ++i) s = fmaf(h[i], wp[i], s);
#pragma unroll
    for (int m = 32; m >= 1; m >>= 1) s += __shfl_xor(s, m);
    lg[e] = s + rb[e];
  }
  if (lane == 0) {
    float v1 = lg[0]; int e1 = 0;
#pragma unroll
    for (int e = 1; e < 8; ++e) {
      if (lg[e] > v1) { v1 = lg[e]; e1 = e; }
    }
    float v2 = -INFINITY; int es = 0;
#pragma unroll
    for (int e = 0; e < 8; ++e) {
      if (e != e1 && lg[e] > v2) { v2 = lg[e]; es = e; }
    }
    float ed = expf(v2 - v1);
    float g1 = 1.f / (1.f + ed);
    float g2 = ed / (1.f + ed);
    int a0 = t * 2, a1 = t * 2 + 1;
    gates[a0] = g1;
    gates[a1] = g2;
    int p = atomicAdd(&counts[e1], 1);
    lists[e1 * 4096 + p] = a0;
    p = atomicAdd(&counts[es], 1);
    lists[es * 4096 + p] = a1;
  }
}

// ---------------- combine: x_next[t] = ybuf[2t] + ybuf[2t+1] ----------------
__global__ __launch_bounds__(256)
void combine_kernel(const float* __restrict__ ybuf, float* __restrict__ out)
{
  int i = blockIdx.x * 256 + threadIdx.x;
  int fi = i * 4;
  int t = fi / 768;
  int d = fi % 768;
  float4 y0 = *(const float4*)&ybuf[(size_t)(2 * t) * 768 + d];
  float4 y1 = *(const float4*)&ybuf[(size_t)(2 * t + 1) * 768 + d];
  float4 r = make_float4(y0.x + y1.x, y0.y + y1.y, y0.z + y1.z, y0.w + y1.w);
  *(float4*)&out[fi] = r;
}

// ---------------- host ----------------
extern "C" void kernel_launch(void* const* d_in, const int* in_sizes, int n_in,
                              void* d_out, int out_size, void* d_ws, size_t ws_size,
                              hipStream_t stream) {
  (void)in_sizes; (void)n_in; (void)out_size; (void)ws_size;
  const float* x      = (const float*)d_in[0];
  const float* proj_W = (const float*)d_in[1];
  const float* proj_b = (const float*)d_in[2];
  const float* Wih    = (const float*)d_in[3];
  const float* Whh    = (const float*)d_in[4];
  const float* bih    = (const float*)d_in[5];
  const float* bhh    = (const float*)d_in[6];
  const float* rW     = (const float*)d_in[7];
  const float* rb     = (const float*)d_in[8];
  const float* eW1    = (const float*)d_in[9];
  const float* eb1    = (const float*)d_in[10];
  const float* eW2    = (const float*)d_in[11];
  const float* eb2    = (const float*)d_in[12];
  float* out = (float*)d_out;

  // workspace layout
  float* f = (float*)d_ws;
  float* h_in  = f;                    // 1,572,864
  float* gi2   = h_in + 1572864;       // 4,718,592
  float* h_seq = gi2 + 4718592;        // 1,572,864
  float* x_buf = h_seq + 1572864;      // 1,572,864
  float* ybuf  = x_buf + 1572864;      // 3,145,728
  float* hbuf  = ybuf + 3145728;       // 6,144
  float* gates = hbuf + 6144;          // 4,096
  short* xh    = (short*)(gates + 4096);  // 1,572,864 shorts
  short* xl    = xh + 1572864;            // 1,572,864 shorts
  short* H1h   = xl + 1572864;            // 12,582,912 shorts
  short* H1l   = H1h + 12582912;          // 12,582,912 shorts
  int* ints    = (int*)(H1l + 12582912);
  int* counts  = ints;                 // 16
  int* lists   = ints + 16;            // 8*4096
  int* tags    = ints + 16 + 32768;    // 96*32 tags

  reset_kernel<<<25, 256, 0, stream>>>(tags, counts, hbuf);

  for (int l = 0; l < 2; ++l) {
    const float* xin = l ? x_buf : x;

    dim3 g1(6, 16);
    gemm_nt<false><<<g1, 256, 0, stream>>>(
        xin, proj_W + (size_t)l * 768 * 768, proj_b + l * 768, h_in,
        768, 768, 768);

    dim3 g2(18, 16);
    gemm_nt<true><<<g2, 256, 0, stream>>>(
        h_in, Wih, bih, gi2, 768, 768, 0);

    gru_kernel<<<96, 512, 0, stream>>>(gi2, h_seq, hbuf, Whh, bhh,
                                       tags, l * 512);

    router_kernel<<<2048, 64, 0, stream>>>(h_seq, rW + (size_t)l * 8 * 768,
                                           rb + l * 8, counts + l * 8, lists, gates);

    split_kernel<<<1536, 256, 0, stream>>>(xin, xh, xl, 393216);

    dim3 ga(24, 32, 8);
    gemm_mfma<true, true, false, true><<<ga, 256, 0, stream>>>(
        xh, xl, eW1 + (size_t)l * 8 * 3072 * 768, eb1 + (size_t)l * 8 * 3072,
        nullptr, H1h, H1l, 768, 768, 3072,
        lists, counts + l * 8, nullptr, (long)3072 * 768, 3072);

    dim3 gb(6, 32, 8);
    gemm_mfma<false, false, true, false><<<gb, 256, 0, stream>>>(
        H1h, H1l, eW2 + (size_t)l * 8 * 768 * 3072, eb2 + (size_t)l * 8 * 768,
        ybuf, nullptr, nullptr, 3072, 3072, 768,
        lists, counts + l * 8, gates, (long)768 * 3072, 768);

    combine_kernel<<<1536, 256, 0, stream>>>(ybuf, l ? out : x_buf);
  }
}

// Round 15
// 5449.236 us; speedup vs baseline: 1.4068x; 1.1140x over previous
//
#include <hip/hip_runtime.h>
#include <cmath>

#define AGENT __HIP_MEMORY_SCOPE_AGENT

// Problem constants
// B=4, S=512, I=H=768, 3H=2304, E=8, K=2, L=2, tokens=2048, assignments=4096

typedef __attribute__((ext_vector_type(8))) short short8;
typedef __attribute__((ext_vector_type(4))) float f32x4;

// ---------------- reset ----------------
__global__ void reset_kernel(int* __restrict__ flags, int* __restrict__ counts,
                             float* __restrict__ hbuf0) {
  int i = blockIdx.x * 256 + threadIdx.x;
  if (i < 6208) flags[i] = 0;          // tags[96*32] + slack
  if (i < 16) counts[i] = 0;           // counts[2][8]
  if (i < 3072) hbuf0[i] = 0.f;        // h0 = zeros (parity 0, all 4 b)
}

// ---------------- split fp32 -> bf16 hi/lo planes ----------------
__global__ __launch_bounds__(256)
void split_kernel(const float* __restrict__ in, short* __restrict__ hi,
                  short* __restrict__ lo, int n4) {
  int i = blockIdx.x * 256 + threadIdx.x;
  if (i >= n4) return;
  float4 v = ((const float4*)in)[i];
  unsigned ua = __float_as_uint(v.x), ub = __float_as_uint(v.y);
  unsigned uc = __float_as_uint(v.z), ud = __float_as_uint(v.w);
  unsigned ha = ua & 0xFFFF0000u, hb = ub & 0xFFFF0000u;
  unsigned hc = uc & 0xFFFF0000u, hd = ud & 0xFFFF0000u;
  unsigned hp0 = (ua >> 16) | hb;
  unsigned hp1 = (uc >> 16) | hd;
  float la = v.x - __uint_as_float(ha), lb = v.y - __uint_as_float(hb);
  float lc = v.z - __uint_as_float(hc), ld = v.w - __uint_as_float(hd);
  unsigned lp0 = (__float_as_uint(la) >> 16) | (__float_as_uint(lb) & 0xFFFF0000u);
  unsigned lp1 = (__float_as_uint(lc) >> 16) | (__float_as_uint(ld) & 0xFFFF0000u);
  ((uint2*)hi)[i] = make_uint2(hp0, hp1);
  ((uint2*)lo)[i] = make_uint2(lp0, lp1);
}

// ---------------- dense fp32 GEMM (proj / gi) ----------------
// C = A @ B^T + bias. Tile 128x128x16, 256 threads, 8x8 acc/thread.
// GI3: remap C store to gi3[t][b][wv(0..191)][gate][4] for the grouped GRU.
template<bool GI3>
__global__ __launch_bounds__(256)
void gemm_nt(const float* __restrict__ A, const float* __restrict__ Bw,
             const float* __restrict__ bias, float* __restrict__ C,
             int Kd, int lda, int ldc)
{
  __shared__ float As[16][132];
  __shared__ float Bs[16][132];

  int mbase = blockIdx.y * 128;
  int nbase = blockIdx.x * 128;
  int tid = threadIdx.x;
  int tx = tid & 15, ty = tid >> 4;

  const float* ap[2];
  const float* bp[2];
  int ldst[2];
#pragma unroll
  for (int i = 0; i < 2; ++i) {
    int v = tid + 256 * i;
    int row = v >> 2, kq = v & 3;
    ap[i] = A + (size_t)(mbase + row) * lda + kq * 4;
    bp[i] = Bw + (size_t)(nbase + row) * Kd + kq * 4;
    ldst[i] = kq * 4 * 132 + row;
  }

  float acc[8][8];
#pragma unroll
  for (int i = 0; i < 8; ++i)
#pragma unroll
    for (int j = 0; j < 8; ++j) acc[i][j] = 0.f;

  for (int kb = 0; kb < Kd; kb += 16) {
    float4 av[2], bv[2];
#pragma unroll
    for (int i = 0; i < 2; ++i) {
      av[i] = *(const float4*)(ap[i] + kb);
      bv[i] = *(const float4*)(bp[i] + kb);
    }
    if (kb) __syncthreads();
#pragma unroll
    for (int i = 0; i < 2; ++i) {
      float* ad = &As[0][0] + ldst[i];
      ad[0] = av[i].x; ad[132] = av[i].y; ad[264] = av[i].z; ad[396] = av[i].w;
      float* bd = &Bs[0][0] + ldst[i];
      bd[0] = bv[i].x; bd[132] = bv[i].y; bd[264] = bv[i].z; bd[396] = bv[i].w;
    }
    __syncthreads();
#pragma unroll
    for (int kk = 0; kk < 16; ++kk) {
      float a[8], b[8];
      *(float4*)&a[0] = *(const float4*)&As[kk][ty * 4];
      *(float4*)&a[4] = *(const float4*)&As[kk][ty * 4 + 64];
      *(float4*)&b[0] = *(const float4*)&Bs[kk][tx * 4];
      *(float4*)&b[4] = *(const float4*)&Bs[kk][tx * 4 + 64];
#pragma unroll
      for (int i = 0; i < 8; ++i)
#pragma unroll
        for (int j = 0; j < 8; ++j)
          acc[i][j] = fmaf(a[i], b[j], acc[i][j]);
    }
  }

#pragma unroll
  for (int i = 0; i < 8; ++i) {
    int lrow = ty * 4 + (i & 3) + ((i >> 2) << 6);
    int grow = mbase + lrow;
#pragma unroll
    for (int q = 0; q < 2; ++q) {
      int col = nbase + tx * 4 + (q << 6);
      float4 bb = *(const float4*)&bias[col];
      float4 st = make_float4(acc[i][q * 4 + 0] + bb.x, acc[i][q * 4 + 1] + bb.y,
                              acc[i][q * 4 + 2] + bb.z, acc[i][q * 4 + 3] + bb.w);
      if constexpr (GI3) {
        int t = grow & 511, bb2 = grow >> 9;
        int gate = col / 768, jj = col - gate * 768;   // jj%4==0
        int wv = jj >> 2;
        float* dst = C + ((((size_t)t * 4 + bb2) * 192 + wv) * 12 + gate * 4);
        *(float4*)dst = st;
      } else {
        *(float4*)&C[(size_t)grow * ldc + col] = st;
      }
    }
  }
}

// ---------------- split-bf16 MFMA expert GEMM (round-14 proven) ----------
template<bool SHIFT, bool RELU, bool GATE, bool OUTSPLIT>
__global__ __launch_bounds__(256)
void gemm_mfma(const short* __restrict__ Ah_g, const short* __restrict__ Al_g,
               const float* __restrict__ Bw, const float* __restrict__ bias,
               float* __restrict__ C, short* __restrict__ Ch,
               short* __restrict__ Cl, int Kd, int lda, int ldc,
               const int* __restrict__ list, const int* __restrict__ count,
               const float* __restrict__ gates, long wstride, int bstride)
{
  __shared__ __align__(16) short Ah[128][40];
  __shared__ __align__(16) short Al[128][40];
  __shared__ __align__(16) short Bh[128][40];
  __shared__ __align__(16) short Bl[128][40];
  __shared__ int rowlist[128];

  int e = blockIdx.z;
  int cnt = count[e];
  int mbase = blockIdx.y * 128;
  if (mbase >= cnt) return;
  int nbase = blockIdx.x * 128;
  const float* Bp = Bw + (size_t)e * (size_t)wstride;
  const float* biasp = bias + (size_t)e * (size_t)bstride;

  int tid = threadIdx.x;
  if (tid < 128) {
    int r = mbase + tid;
    rowlist[tid] = list[e * 4096 + (r < cnt ? r : cnt - 1)];
  }
  __syncthreads();

  int arow = tid >> 1, ahalf = tid & 1;
  int aidx0 = rowlist[arow];
  int sr = SHIFT ? (aidx0 >> 1) : aidx0;
  const short* aph = Ah_g + (size_t)sr * lda + ahalf * 16;
  const short* apl = Al_g + (size_t)sr * lda + ahalf * 16;
  const float* bp = Bp + (size_t)(nbase + arow) * Kd + ahalf * 16;

  int wave = tid >> 6, lane = tid & 63;
  int wr = (wave >> 1) * 64, wc = (wave & 1) * 64;
  int fr = lane & 15, fo = (lane >> 4) * 8;

  f32x4 acc[4][4];
#pragma unroll
  for (int i = 0; i < 4; ++i)
#pragma unroll
    for (int j = 0; j < 4; ++j) acc[i][j] = f32x4{0.f, 0.f, 0.f, 0.f};

  for (int kb = 0; kb < Kd; kb += 32) {
    uint4 a_h0 = *(const uint4*)(aph + kb);
    uint4 a_h1 = *(const uint4*)(aph + kb + 8);
    uint4 a_l0 = *(const uint4*)(apl + kb);
    uint4 a_l1 = *(const uint4*)(apl + kb + 8);
    float4 b0 = *(const float4*)(bp + kb);
    float4 b1 = *(const float4*)(bp + kb + 4);
    float4 b2 = *(const float4*)(bp + kb + 8);
    float4 b3 = *(const float4*)(bp + kb + 12);
    if (kb) __syncthreads();
    *(uint4*)&Ah[arow][ahalf * 16] = a_h0;
    *(uint4*)&Ah[arow][ahalf * 16 + 8] = a_h1;
    *(uint4*)&Al[arow][ahalf * 16] = a_l0;
    *(uint4*)&Al[arow][ahalf * 16 + 8] = a_l1;
    unsigned hp[8], lp[8];
    const float4 bbv[4] = {b0, b1, b2, b3};
#pragma unroll
    for (int q = 0; q < 4; ++q) {
      unsigned ua = __float_as_uint(bbv[q].x), ub = __float_as_uint(bbv[q].y);
      unsigned uc = __float_as_uint(bbv[q].z), ud = __float_as_uint(bbv[q].w);
      unsigned ha = ua & 0xFFFF0000u, hb = ub & 0xFFFF0000u;
      unsigned hc = uc & 0xFFFF0000u, hd = ud & 0xFFFF0000u;
      hp[q * 2] = (ua >> 16) | hb;
      hp[q * 2 + 1] = (uc >> 16) | hd;
      float la = bbv[q].x - __uint_as_float(ha);
      float lb = bbv[q].y - __uint_as_float(hb);
      float lc = bbv[q].z - __uint_as_float(hc);
      float ld = bbv[q].w - __uint_as_float(hd);
      lp[q * 2] = (__float_as_uint(la) >> 16) | (__float_as_uint(lb) & 0xFFFF0000u);
      lp[q * 2 + 1] = (__float_as_uint(lc) >> 16) | (__float_as_uint(ld) & 0xFFFF0000u);
    }
    *(uint4*)&Bh[arow][ahalf * 16] = make_uint4(hp[0], hp[1], hp[2], hp[3]);
    *(uint4*)&Bh[arow][ahalf * 16 + 8] = make_uint4(hp[4], hp[5], hp[6], hp[7]);
    *(uint4*)&Bl[arow][ahalf * 16] = make_uint4(lp[0], lp[1], lp[2], lp[3]);
    *(uint4*)&Bl[arow][ahalf * 16 + 8] = make_uint4(lp[4], lp[5], lp[6], lp[7]);
    __syncthreads();

    short8 fah[4], fal[4], fbh[4], fbl[4];
#pragma unroll
    for (int mt = 0; mt < 4; ++mt) {
      fah[mt] = *(const short8*)&Ah[wr + mt * 16 + fr][fo];
      fal[mt] = *(const short8*)&Al[wr + mt * 16 + fr][fo];
    }
#pragma unroll
    for (int nt = 0; nt < 4; ++nt) {
      fbh[nt] = *(const short8*)&Bh[wc + nt * 16 + fr][fo];
      fbl[nt] = *(const short8*)&Bl[wc + nt * 16 + fr][fo];
    }
#pragma unroll
    for (int mt = 0; mt < 4; ++mt)
#pragma unroll
      for (int nt = 0; nt < 4; ++nt) {
        acc[mt][nt] = __builtin_amdgcn_mfma_f32_16x16x32_bf16(fah[mt], fbh[nt], acc[mt][nt], 0, 0, 0);
        acc[mt][nt] = __builtin_amdgcn_mfma_f32_16x16x32_bf16(fah[mt], fbl[nt], acc[mt][nt], 0, 0, 0);
        acc[mt][nt] = __builtin_amdgcn_mfma_f32_16x16x32_bf16(fal[mt], fbh[nt], acc[mt][nt], 0, 0, 0);
      }
  }

  int crow = (lane >> 4) * 4;
#pragma unroll
  for (int mt = 0; mt < 4; ++mt) {
#pragma unroll
    for (int q = 0; q < 4; ++q) {
      int lrow = wr + mt * 16 + crow + q;
      int grow = mbase + lrow;
      if (grow < cnt) {
        int aidx = rowlist[lrow];
#pragma unroll
        for (int nt = 0; nt < 4; ++nt) {
          int col = nbase + wc + nt * 16 + fr;
          float v = acc[mt][nt][q] + biasp[col];
          if (RELU) v = fmaxf(v, 0.f);
          if (GATE) v *= gates[aidx];
          if (OUTSPLIT) {
            unsigned u = __float_as_uint(v);
            unsigned h = u & 0xFFFF0000u;
            Ch[(size_t)aidx * ldc + col] = (short)(u >> 16);
            float l2 = v - __uint_as_float(h);
            Cl[(size_t)aidx * ldc + col] = (short)(__float_as_uint(l2) >> 16);
          } else {
            C[(size_t)aidx * ldc + col] = v;
          }
        }
      }
    }
  }
}

// ---------------- GRU persistent kernel: 4 independent batch groups ------
// 96 WGs x 512 threads = 4 groups x 24 WGs; group b owns batch chain b
// (h[b][t] depends only on h[b][t-1] -> groups fully decoupled).
// Wave wv = wgi*8+wave owns cols [wv*4, wv*4+4) of batch b.
// Per step: poll 24 group tags -> load h[b] (3KB, 192 float4 coherent) into
// LDS -> 144 FMA + 12 butterfly reduces -> lanes 0..3 gate math ->
// 4 coherent stores -> tag publish. Barrier scope 24 WGs (was 96);
// 4 group pipelines overlap in the fabric.
__global__ __launch_bounds__(512, 2)
void gru_kernel(const float* __restrict__ gi3, float* __restrict__ h_seq,
                float* __restrict__ hbuf, const float* __restrict__ Whh,
                const float* __restrict__ bhh,
                int* __restrict__ tags, int stepBase)
{
  const int H = 768, S = 512;
  __shared__ float hs[768];
  int wg = blockIdx.x;           // 0..95
  int b = wg / 24;               // batch group 0..3
  int wgi = wg - b * 24;         // 0..23 within group
  int tid = threadIdx.x;         // 0..511
  int wave = tid >> 6;           // 0..7
  int lane = tid & 63;
  int wv = wgi * 8 + wave;       // 0..191: owns cols wv*4..wv*4+3

  // W[c][g][q*4+k4] = Whh[g*H + (wv*4+c)][q*256 + lane*4 + k4]
  float W[4][3][12];
#pragma unroll
  for (int c = 0; c < 4; ++c)
#pragma unroll
    for (int g = 0; g < 3; ++g) {
      const float* wp = Whh + (size_t)(g * H + wv * 4 + c) * H + lane * 4;
      *(float4*)&W[c][g][0] = *(const float4*)(wp);
      *(float4*)&W[c][g][4] = *(const float4*)(wp + 256);
      *(float4*)&W[c][g][8] = *(const float4*)(wp + 512);
    }
  int mycol = wv * 4 + (lane & 3);
  float bh_r = bhh[mycol], bh_z = bhh[H + mycol], bh_n = bhh[2 * H + mycol];

  float h_own = 0.f;
  if (lane < 4)
    h_own = __hip_atomic_load(&hbuf[(stepBase & 1) * 3072 + b * H + mycol],
                              __ATOMIC_RELAXED, AGENT);

  for (int tl = 0; tl < S; ++tl) {
    int g = stepBase + tl;
    const float* hb = hbuf + (g & 1) * 3072 + b * H;
    float* hw = hbuf + ((g + 1) & 1) * 3072 + b * H;

    // gi prefetch: lanes 0..11 load this wave's 12 gi floats [gate][4cols]
    float gv = 0.f;
    if (lane < 12)
      gv = gi3[((((size_t)tl * 4 + b) * 192 + wv) * 12) + lane];

    // ---- tag poll: wave0 waits for this group's 24 producers ----
    if (wave == 0) {
      for (;;) {
        int v1 = (lane < 24)
            ? __hip_atomic_load(&tags[(b * 24 + lane) * 32], __ATOMIC_RELAXED, AGENT)
            : 0x7fffffff;
        if (__all(v1 >= g)) break;
        __builtin_amdgcn_s_sleep(2);
      }
    }
    __syncthreads();

    // ---- stage h[b] into LDS: 192 coherent float4 loads ----
    float4 a = make_float4(0.f, 0.f, 0.f, 0.f);
    if (tid < 192)   // waves 0..2: wave-uniform
      asm volatile("global_load_dwordx4 %0, %1, off sc0 sc1"
                   : "=v"(a) : "v"(hb + tid * 4) : "memory");
    asm volatile("s_waitcnt vmcnt(0)" ::: "memory");
    __builtin_amdgcn_sched_barrier(0);
    if (tid < 192) *(float4*)&hs[tid * 4] = a;
    __syncthreads();

    // ---- sharded h_seq write of h[b][tl-1] (off critical path) ----
    if (tl >= 1 && tid >= wgi * 8 && tid < wgi * 8 + 8)
      *(float4*)&h_seq[((size_t)b * S + (tl - 1)) * H + tid * 4] = a;

    // ---- fragments from LDS (shared k-slice for all 4 cols) ----
    float hseg[12];
    *(float4*)&hseg[0] = *(const float4*)&hs[lane * 4];
    *(float4*)&hseg[4] = *(const float4*)&hs[256 + lane * 4];
    *(float4*)&hseg[8] = *(const float4*)&hs[512 + lane * 4];

    float acc[4][3];
#pragma unroll
    for (int c = 0; c < 4; ++c)
#pragma unroll
      for (int gg = 0; gg < 3; ++gg) {
        float s = 0.f;
#pragma unroll
        for (int i = 0; i < 12; ++i) s = fmaf(W[c][gg][i], hseg[i], s);
        acc[c][gg] = s;
      }
#pragma unroll
    for (int c = 0; c < 4; ++c)
#pragma unroll
      for (int gg = 0; gg < 3; ++gg) {
        float v = acc[c][gg];
#pragma unroll
        for (int m = 32; m >= 1; m >>= 1) v += __shfl_xor(v, m);
        acc[c][gg] = v;
      }

    float gi_r = __shfl(gv, (lane & 3));
    float gi_z = __shfl(gv, 4 + (lane & 3));
    float gi_n = __shfl(gv, 8 + (lane & 3));

    if (lane < 4) {
      float ar = acc[0][0], az = acc[0][1], an = acc[0][2];
      if (lane == 1) { ar = acc[1][0]; az = acc[1][1]; an = acc[1][2]; }
      if (lane == 2) { ar = acc[2][0]; az = acc[2][1]; an = acc[2][2]; }
      if (lane == 3) { ar = acc[3][0]; az = acc[3][1]; an = acc[3][2]; }
      float r = 1.f / (1.f + expf(-(gi_r + ar + bh_r)));
      float z = 1.f / (1.f + expf(-(gi_z + az + bh_z)));
      float n = tanhf(gi_n + r * (an + bh_n));
      float hn = (1.f - z) * n + z * h_own;
      h_own = hn;
      __hip_atomic_store(&hw[mycol], hn, __ATOMIC_RELAXED, AGENT);
    }

    // ---- publish: own h stores acked -> all waves joined -> tag ----
    asm volatile("s_waitcnt vmcnt(0)" ::: "memory");
    __syncthreads();
    if (tid == 0)
      __hip_atomic_store(&tags[(b * 24 + wgi) * 32], g + 1, __ATOMIC_RELAXED, AGENT);
  }

  // epilogue: write h[b][S-1] from registers
  if (lane < 4)
    h_seq[((size_t)b * S + (S - 1)) * H + mycol] = h_own;
}

// ---------------- router + top-2 + gates + expert lists ----------------
__global__ __launch_bounds__(64)
void router_kernel(const float* __restrict__ h_seq, const float* __restrict__ rW,
                   const float* __restrict__ rb, int* __restrict__ counts,
                   int* __restrict__ lists, float* __restrict__ gates)
{
  int t = blockIdx.x;
  int lane = threadIdx.x;
  const float* hp = h_seq + (size_t)t * 768 + lane * 12;
  float h[12];
  *(float4*)&h[0] = *(const float4*)(hp);
  *(float4*)&h[4] = *(const float4*)(hp + 4);
  *(float4*)&h[8] = *(const float4*)(hp + 8);

  float lg[8];
#pragma unroll
  for (int e = 0; e < 8; ++e) {
    const float* wp = rW + e * 768 + lane * 12;
    float s = 0.f;
#pragma unroll
    for (int i = 0; i < 12; ++i) s = fmaf(h[i], wp[i], s);
#pragma unroll
    for (int m = 32; m >= 1; m >>= 1) s += __shfl_xor(s, m);
    lg[e] = s + rb[e];
  }
  if (lane == 0) {
    float v1 = lg[0]; int e1 = 0;
#pragma unroll
    for (int e = 1; e < 8; ++e) {
      if (lg[e] > v1) { v1 = lg[e]; e1 = e; }
    }
    float v2 = -INFINITY; int es = 0;
#pragma unroll
    for (int e = 0; e < 8; ++e) {
      if (e != e1 && lg[e] > v2) { v2 = lg[e]; es = e; }
    }
    float ed = expf(v2 - v1);
    float g1 = 1.f / (1.f + ed);
    float g2 = ed / (1.f + ed);
    int a0 = t * 2, a1 = t * 2 + 1;
    gates[a0] = g1;
    gates[a1] = g2;
    int p = atomicAdd(&counts[e1], 1);
    lists[e1 * 4096 + p] = a0;
    p = atomicAdd(&counts[es], 1);
    lists[es * 4096 + p] = a1;
  }
}

// ---------------- combine: x_next[t] = ybuf[2t] + ybuf[2t+1] ----------------
__global__ __launch_bounds__(256)
void combine_kernel(const float* __restrict__ ybuf, float* __restrict__ out)
{
  int i = blockIdx.x * 256 + threadIdx.x;
  int fi = i * 4;
  int t = fi / 768;
  int d = fi % 768;
  float4 y0 = *(const float4*)&ybuf[(size_t)(2 * t) * 768 + d];
  float4 y1 = *(const float4*)&ybuf[(size_t)(2 * t + 1) * 768 + d];
  float4 r = make_float4(y0.x + y1.x, y0.y + y1.y, y0.z + y1.z, y0.w + y1.w);
  *(float4*)&out[fi] = r;
}

// ---------------- host ----------------
extern "C" void kernel_launch(void* const* d_in, const int* in_sizes, int n_in,
                              void* d_out, int out_size, void* d_ws, size_t ws_size,
                              hipStream_t stream) {
  (void)in_sizes; (void)n_in; (void)out_size; (void)ws_size;
  const float* x      = (const float*)d_in[0];
  const float* proj_W = (const float*)d_in[1];
  const float* proj_b = (const float*)d_in[2];
  const float* Wih    = (const float*)d_in[3];
  const float* Whh    = (const float*)d_in[4];
  const float* bih    = (const float*)d_in[5];
  const float* bhh    = (const float*)d_in[6];
  const float* rW     = (const float*)d_in[7];
  const float* rb     = (const float*)d_in[8];
  const float* eW1    = (const float*)d_in[9];
  const float* eb1    = (const float*)d_in[10];
  const float* eW2    = (const float*)d_in[11];
  const float* eb2    = (const float*)d_in[12];
  float* out = (float*)d_out;

  // workspace layout
  float* f = (float*)d_ws;
  float* h_in  = f;                    // 1,572,864
  float* gi3   = h_in + 1572864;       // 512*4*192*12 = 4,718,592
  float* h_seq = gi3 + 4718592;        // 1,572,864
  float* x_buf = h_seq + 1572864;      // 1,572,864
  float* ybuf  = x_buf + 1572864;      // 3,145,728
  float* hbuf  = ybuf + 3145728;       // 6,144 ([2 parity][4 b][768])
  float* gates = hbuf + 6144;          // 4,096
  short* xh    = (short*)(gates + 4096);  // 1,572,864 shorts
  short* xl    = xh + 1572864;            // 1,572,864 shorts
  short* H1h   = xl + 1572864;            // 12,582,912 shorts
  short* H1l   = H1h + 12582912;          // 12,582,912 shorts
  int* ints    = (int*)(H1l + 12582912);
  int* counts  = ints;                 // 16
  int* lists   = ints + 16;            // 8*4096
  int* tags    = ints + 16 + 32768;    // 96*32 tags

  reset_kernel<<<25, 256, 0, stream>>>(tags, counts, hbuf);

  for (int l = 0; l < 2; ++l) {
    const float* xin = l ? x_buf : x;

    dim3 g1(6, 16);
    gemm_nt<false><<<g1, 256, 0, stream>>>(
        xin, proj_W + (size_t)l * 768 * 768, proj_b + l * 768, h_in,
        768, 768, 768);

    dim3 g2(18, 16);
    gemm_nt<true><<<g2, 256, 0, stream>>>(
        h_in, Wih, bih, gi3, 768, 768, 0);

    gru_kernel<<<96, 512, 0, stream>>>(gi3, h_seq, hbuf, Whh, bhh,
                                       tags, l * 512);

    router_kernel<<<2048, 64, 0, stream>>>(h_seq, rW + (size_t)l * 8 * 768,
                                           rb + l * 8, counts + l * 8, lists, gates);

    split_kernel<<<1536, 256, 0, stream>>>(xin, xh, xl, 393216);

    dim3 ga(24, 32, 8);
    gemm_mfma<true, true, false, true><<<ga, 256, 0, stream>>>(
        xh, xl, eW1 + (size_t)l * 8 * 3072 * 768, eb1 + (size_t)l * 8 * 3072,
        nullptr, H1h, H1l, 768, 768, 3072,
        lists, counts + l * 8, nullptr, (long)3072 * 768, 3072);

    dim3 gb(6, 32, 8);
    gemm_mfma<false, false, true, false><<<gb, 256, 0, stream>>>(
        H1h, H1l, eW2 + (size_t)l * 8 * 768 * 3072, eb2 + (size_t)l * 8 * 768,
        ybuf, nullptr, nullptr, 3072, 3072, 768,
        lists, counts + l * 8, gates, (long)768 * 3072, 768);

    combine_kernel<<<1536, 256, 0, stream>>>(ybuf, l ? out : x_buf);
  }
}

// Round 17
// 4925.502 us; speedup vs baseline: 1.5564x; 1.1063x over previous
//
#include <hip/hip_runtime.h>
#include <cmath>

#define AGENT __HIP_MEMORY_SCOPE_AGENT

// Problem constants
// B=4, S=512, I=H=768, 3H=2304, E=8, K=2, L=2, tokens=2048, assignments=4096

typedef __attribute__((ext_vector_type(8))) short short8;
typedef __attribute__((ext_vector_type(4))) float f32x4;

// ---------------- reset: NaN-fill hstep (COHERENT), zero zbuf, counts ----
// ALL hstep/zbuf accesses everywhere are sc0 sc1 / relaxed-agent (LLC) —
// no plain/coherent aliasing (round-9's stale-L2 deadlock excluded).
// NOTE: clang can't take vector-typed asm INPUTS ("v"(uint4)) — use scalar
// __hip_atomic_store (relaxed) which emits global_store_dword sc0 sc1.
__global__ __launch_bounds__(256)
void reset_kernel(float* __restrict__ hstep, float* __restrict__ zbuf,
                  int* __restrict__ counts) {
  int i = blockIdx.x * 256 + threadIdx.x;
  if (i < 786432) {   // 2 layers * 512 * 3072 floats / 4
    float qn = __uint_as_float(0x7FC00000u);
    float* p = hstep + (size_t)i * 4;
    __hip_atomic_store(p + 0, qn, __ATOMIC_RELAXED, AGENT);
    __hip_atomic_store(p + 1, qn, __ATOMIC_RELAXED, AGENT);
    __hip_atomic_store(p + 2, qn, __ATOMIC_RELAXED, AGENT);
    __hip_atomic_store(p + 3, qn, __ATOMIC_RELAXED, AGENT);
  }
  if (i < 768) {      // zbuf [4][768] zeros
    float* p = zbuf + (size_t)i * 4;
    __hip_atomic_store(p + 0, 0.f, __ATOMIC_RELAXED, AGENT);
    __hip_atomic_store(p + 1, 0.f, __ATOMIC_RELAXED, AGENT);
    __hip_atomic_store(p + 2, 0.f, __ATOMIC_RELAXED, AGENT);
    __hip_atomic_store(p + 3, 0.f, __ATOMIC_RELAXED, AGENT);
  }
  if (i < 16) counts[i] = 0;
}

// ---------------- split fp32 -> bf16 hi/lo planes ----------------
__global__ __launch_bounds__(256)
void split_kernel(const float* __restrict__ in, short* __restrict__ hi,
                  short* __restrict__ lo, int n4) {
  int i = blockIdx.x * 256 + threadIdx.x;
  if (i >= n4) return;
  float4 v = ((const float4*)in)[i];
  unsigned ua = __float_as_uint(v.x), ub = __float_as_uint(v.y);
  unsigned uc = __float_as_uint(v.z), ud = __float_as_uint(v.w);
  unsigned ha = ua & 0xFFFF0000u, hb = ub & 0xFFFF0000u;
  unsigned hc = uc & 0xFFFF0000u, hd = ud & 0xFFFF0000u;
  unsigned hp0 = (ua >> 16) | hb;
  unsigned hp1 = (uc >> 16) | hd;
  float la = v.x - __uint_as_float(ha), lb = v.y - __uint_as_float(hb);
  float lc = v.z - __uint_as_float(hc), ld = v.w - __uint_as_float(hd);
  unsigned lp0 = (__float_as_uint(la) >> 16) | (__float_as_uint(lb) & 0xFFFF0000u);
  unsigned lp1 = (__float_as_uint(lc) >> 16) | (__float_as_uint(ld) & 0xFFFF0000u);
  ((uint2*)hi)[i] = make_uint2(hp0, hp1);
  ((uint2*)lo)[i] = make_uint2(lp0, lp1);
}

// ---------------- dense fp32 GEMM (proj / gi) ----------------
template<bool GI3>
__global__ __launch_bounds__(256)
void gemm_nt(const float* __restrict__ A, const float* __restrict__ Bw,
             const float* __restrict__ bias, float* __restrict__ C,
             int Kd, int lda, int ldc)
{
  __shared__ float As[16][132];
  __shared__ float Bs[16][132];

  int mbase = blockIdx.y * 128;
  int nbase = blockIdx.x * 128;
  int tid = threadIdx.x;
  int tx = tid & 15, ty = tid >> 4;

  const float* ap[2];
  const float* bp[2];
  int ldst[2];
#pragma unroll
  for (int i = 0; i < 2; ++i) {
    int v = tid + 256 * i;
    int row = v >> 2, kq = v & 3;
    ap[i] = A + (size_t)(mbase + row) * lda + kq * 4;
    bp[i] = Bw + (size_t)(nbase + row) * Kd + kq * 4;
    ldst[i] = kq * 4 * 132 + row;
  }

  float acc[8][8];
#pragma unroll
  for (int i = 0; i < 8; ++i)
#pragma unroll
    for (int j = 0; j < 8; ++j) acc[i][j] = 0.f;

  for (int kb = 0; kb < Kd; kb += 16) {
    float4 av[2], bv[2];
#pragma unroll
    for (int i = 0; i < 2; ++i) {
      av[i] = *(const float4*)(ap[i] + kb);
      bv[i] = *(const float4*)(bp[i] + kb);
    }
    if (kb) __syncthreads();
#pragma unroll
    for (int i = 0; i < 2; ++i) {
      float* ad = &As[0][0] + ldst[i];
      ad[0] = av[i].x; ad[132] = av[i].y; ad[264] = av[i].z; ad[396] = av[i].w;
      float* bd = &Bs[0][0] + ldst[i];
      bd[0] = bv[i].x; bd[132] = bv[i].y; bd[264] = bv[i].z; bd[396] = bv[i].w;
    }
    __syncthreads();
#pragma unroll
    for (int kk = 0; kk < 16; ++kk) {
      float a[8], b[8];
      *(float4*)&a[0] = *(const float4*)&As[kk][ty * 4];
      *(float4*)&a[4] = *(const float4*)&As[kk][ty * 4 + 64];
      *(float4*)&b[0] = *(const float4*)&Bs[kk][tx * 4];
      *(float4*)&b[4] = *(const float4*)&Bs[kk][tx * 4 + 64];
#pragma unroll
      for (int i = 0; i < 8; ++i)
#pragma unroll
        for (int j = 0; j < 8; ++j)
          acc[i][j] = fmaf(a[i], b[j], acc[i][j]);
    }
  }

#pragma unroll
  for (int i = 0; i < 8; ++i) {
    int lrow = ty * 4 + (i & 3) + ((i >> 2) << 6);
    int grow = mbase + lrow;
#pragma unroll
    for (int q = 0; q < 2; ++q) {
      int col = nbase + tx * 4 + (q << 6);
      float4 bb = *(const float4*)&bias[col];
      float4 st = make_float4(acc[i][q * 4 + 0] + bb.x, acc[i][q * 4 + 1] + bb.y,
                              acc[i][q * 4 + 2] + bb.z, acc[i][q * 4 + 3] + bb.w);
      if constexpr (GI3) {
        int t = grow & 511, bb2 = grow >> 9;
        int gate = col / 768, jj = col - gate * 768;   // jj%4==0
        int wv = jj >> 2;
        float* dst = C + ((((size_t)t * 4 + bb2) * 192 + wv) * 12 + gate * 4);
        *(float4*)dst = st;
      } else {
        *(float4*)&C[(size_t)grow * ldc + col] = st;
      }
    }
  }
}

// ---------------- split-bf16 MFMA expert GEMM (round-14 proven) ----------
template<bool SHIFT, bool RELU, bool GATE, bool OUTSPLIT>
__global__ __launch_bounds__(256)
void gemm_mfma(const short* __restrict__ Ah_g, const short* __restrict__ Al_g,
               const float* __restrict__ Bw, const float* __restrict__ bias,
               float* __restrict__ C, short* __restrict__ Ch,
               short* __restrict__ Cl, int Kd, int lda, int ldc,
               const int* __restrict__ list, const int* __restrict__ count,
               const float* __restrict__ gates, long wstride, int bstride)
{
  __shared__ __align__(16) short Ah[128][40];
  __shared__ __align__(16) short Al[128][40];
  __shared__ __align__(16) short Bh[128][40];
  __shared__ __align__(16) short Bl[128][40];
  __shared__ int rowlist[128];

  int e = blockIdx.z;
  int cnt = count[e];
  int mbase = blockIdx.y * 128;
  if (mbase >= cnt) return;
  int nbase = blockIdx.x * 128;
  const float* Bp = Bw + (size_t)e * (size_t)wstride;
  const float* biasp = bias + (size_t)e * (size_t)bstride;

  int tid = threadIdx.x;
  if (tid < 128) {
    int r = mbase + tid;
    rowlist[tid] = list[e * 4096 + (r < cnt ? r : cnt - 1)];
  }
  __syncthreads();

  int arow = tid >> 1, ahalf = tid & 1;
  int aidx0 = rowlist[arow];
  int sr = SHIFT ? (aidx0 >> 1) : aidx0;
  const short* aph = Ah_g + (size_t)sr * lda + ahalf * 16;
  const short* apl = Al_g + (size_t)sr * lda + ahalf * 16;
  const float* bp = Bp + (size_t)(nbase + arow) * Kd + ahalf * 16;

  int wave = tid >> 6, lane = tid & 63;
  int wr = (wave >> 1) * 64, wc = (wave & 1) * 64;
  int fr = lane & 15, fo = (lane >> 4) * 8;

  f32x4 acc[4][4];
#pragma unroll
  for (int i = 0; i < 4; ++i)
#pragma unroll
    for (int j = 0; j < 4; ++j) acc[i][j] = f32x4{0.f, 0.f, 0.f, 0.f};

  for (int kb = 0; kb < Kd; kb += 32) {
    uint4 a_h0 = *(const uint4*)(aph + kb);
    uint4 a_h1 = *(const uint4*)(aph + kb + 8);
    uint4 a_l0 = *(const uint4*)(apl + kb);
    uint4 a_l1 = *(const uint4*)(apl + kb + 8);
    float4 b0 = *(const float4*)(bp + kb);
    float4 b1 = *(const float4*)(bp + kb + 4);
    float4 b2 = *(const float4*)(bp + kb + 8);
    float4 b3 = *(const float4*)(bp + kb + 12);
    if (kb) __syncthreads();
    *(uint4*)&Ah[arow][ahalf * 16] = a_h0;
    *(uint4*)&Ah[arow][ahalf * 16 + 8] = a_h1;
    *(uint4*)&Al[arow][ahalf * 16] = a_l0;
    *(uint4*)&Al[arow][ahalf * 16 + 8] = a_l1;
    unsigned hp[8], lp[8];
    const float4 bbv[4] = {b0, b1, b2, b3};
#pragma unroll
    for (int q = 0; q < 4; ++q) {
      unsigned ua = __float_as_uint(bbv[q].x), ub = __float_as_uint(bbv[q].y);
      unsigned uc = __float_as_uint(bbv[q].z), ud = __float_as_uint(bbv[q].w);
      unsigned ha = ua & 0xFFFF0000u, hb = ub & 0xFFFF0000u;
      unsigned hc = uc & 0xFFFF0000u, hd = ud & 0xFFFF0000u;
      hp[q * 2] = (ua >> 16) | hb;
      hp[q * 2 + 1] = (uc >> 16) | hd;
      float la = bbv[q].x - __uint_as_float(ha);
      float lb = bbv[q].y - __uint_as_float(hb);
      float lc = bbv[q].z - __uint_as_float(hc);
      float ld = bbv[q].w - __uint_as_float(hd);
      lp[q * 2] = (__float_as_uint(la) >> 16) | (__float_as_uint(lb) & 0xFFFF0000u);
      lp[q * 2 + 1] = (__float_as_uint(lc) >> 16) | (__float_as_uint(ld) & 0xFFFF0000u);
    }
    *(uint4*)&Bh[arow][ahalf * 16] = make_uint4(hp[0], hp[1], hp[2], hp[3]);
    *(uint4*)&Bh[arow][ahalf * 16 + 8] = make_uint4(hp[4], hp[5], hp[6], hp[7]);
    *(uint4*)&Bl[arow][ahalf * 16] = make_uint4(lp[0], lp[1], lp[2], lp[3]);
    *(uint4*)&Bl[arow][ahalf * 16 + 8] = make_uint4(lp[4], lp[5], lp[6], lp[7]);
    __syncthreads();

    short8 fah[4], fal[4], fbh[4], fbl[4];
#pragma unroll
    for (int mt = 0; mt < 4; ++mt) {
      fah[mt] = *(const short8*)&Ah[wr + mt * 16 + fr][fo];
      fal[mt] = *(const short8*)&Al[wr + mt * 16 + fr][fo];
    }
#pragma unroll
    for (int nt = 0; nt < 4; ++nt) {
      fbh[nt] = *(const short8*)&Bh[wc + nt * 16 + fr][fo];
      fbl[nt] = *(const short8*)&Bl[wc + nt * 16 + fr][fo];
    }
#pragma unroll
    for (int mt = 0; mt < 4; ++mt)
#pragma unroll
      for (int nt = 0; nt < 4; ++nt) {
        acc[mt][nt] = __builtin_amdgcn_mfma_f32_16x16x32_bf16(fah[mt], fbh[nt], acc[mt][nt], 0, 0, 0);
        acc[mt][nt] = __builtin_amdgcn_mfma_f32_16x16x32_bf16(fah[mt], fbl[nt], acc[mt][nt], 0, 0, 0);
        acc[mt][nt] = __builtin_amdgcn_mfma_f32_16x16x32_bf16(fal[mt], fbh[nt], acc[mt][nt], 0, 0, 0);
      }
  }

  int crow = (lane >> 4) * 4;
#pragma unroll
  for (int mt = 0; mt < 4; ++mt) {
#pragma unroll
    for (int q = 0; q < 4; ++q) {
      int lrow = wr + mt * 16 + crow + q;
      int grow = mbase + lrow;
      if (grow < cnt) {
        int aidx = rowlist[lrow];
#pragma unroll
        for (int nt = 0; nt < 4; ++nt) {
          int col = nbase + wc + nt * 16 + fr;
          float v = acc[mt][nt][q] + biasp[col];
          if (RELU) v = fmaxf(v, 0.f);
          if (GATE) v *= gates[aidx];
          if (OUTSPLIT) {
            unsigned u = __float_as_uint(v);
            unsigned h = u & 0xFFFF0000u;
            Ch[(size_t)aidx * ldc + col] = (short)(u >> 16);
            float l2 = v - __uint_as_float(h);
            Cl[(size_t)aidx * ldc + col] = (short)(__float_as_uint(l2) >> 16);
          } else {
            C[(size_t)aidx * ldc + col] = v;
          }
        }
      }
    }
  }
}

// ---------------- GRU persistent kernel: NaN-sentinel dataflow -----------
// 4 batch groups x 24 WGs (group b = wg/24 owns batch chain b).
// hstep[t][b][768] pre-filled qNaN; ALL hstep accesses are sc0 sc1 (LLC).
// Producer: lane<4 stores h[t] coherently and proceeds (no ack/tag/barrier).
// Consumer at t: threads 0..191 poll THEIR OWN float4 of hstep[t-1][b]
// until NaN-free (4B dwords flip atomically), stage to LDS, compute.
// Chain per step = one one-way store + one poll sample (was 3 round trips).
// Deadlock-free: producers never wait on consumers; all 96 WGs resident.
__global__ __launch_bounds__(512, 2)
void gru_kernel(const float* __restrict__ gi3, float* __restrict__ h_seq,
                float* __restrict__ hstep, const float* __restrict__ hprev,
                const float* __restrict__ Whh, const float* __restrict__ bhh)
{
  const int H = 768, S = 512;
  __shared__ float hs[768];
  int wg = blockIdx.x;           // 0..95
  int b = wg / 24;               // batch group 0..3
  int wgi = wg - b * 24;         // 0..23 within group
  int tid = threadIdx.x;         // 0..511
  int wave = tid >> 6;           // 0..7
  int lane = tid & 63;
  int wv = wgi * 8 + wave;       // 0..191: owns cols wv*4..wv*4+3

  float W[4][3][12];
#pragma unroll
  for (int c = 0; c < 4; ++c)
#pragma unroll
    for (int g = 0; g < 3; ++g) {
      const float* wp = Whh + (size_t)(g * H + wv * 4 + c) * H + lane * 4;
      *(float4*)&W[c][g][0] = *(const float4*)(wp);
      *(float4*)&W[c][g][4] = *(const float4*)(wp + 256);
      *(float4*)&W[c][g][8] = *(const float4*)(wp + 512);
    }
  int mycol = wv * 4 + (lane & 3);
  float bh_r = bhh[mycol], bh_z = bhh[H + mycol], bh_n = bhh[2 * H + mycol];

  float h_own = 0.f;
  if (lane < 4)
    h_own = __hip_atomic_load(&hprev[b * H + mycol], __ATOMIC_RELAXED, AGENT);

  for (int tl = 0; tl < S; ++tl) {
    // gi prefetch (plain cached load; latency hidden under the poll)
    float gv = 0.f;
    if (lane < 12)
      gv = gi3[((((size_t)tl * 4 + b) * 192 + wv) * 12) + lane];

    // ---- acquire h[tl-1][b]: per-thread coherent NaN-poll (tid<192) ----
    float4 a = make_float4(0.f, 0.f, 0.f, 0.f);
    if (tid < 192) {   // waves 0..2, wave-uniform
      if (tl == 0) {
        asm volatile("global_load_dwordx4 %0, %1, off sc0 sc1"
                     : "=v"(a) : "v"(hprev + b * 768 + tid * 4) : "memory");
        asm volatile("s_waitcnt vmcnt(0)" ::: "memory");
      } else {
        const float* src = hstep + ((size_t)(tl - 1) * 4 + b) * 768 + tid * 4;
        for (;;) {
          asm volatile("global_load_dwordx4 %0, %1, off sc0 sc1"
                       : "=v"(a) : "v"(src) : "memory");
          asm volatile("s_waitcnt vmcnt(0)" ::: "memory");
          if (!((a.x != a.x) | (a.y != a.y) | (a.z != a.z) | (a.w != a.w)))
            break;
          __builtin_amdgcn_s_sleep(1);
        }
      }
    }
    __builtin_amdgcn_sched_barrier(0);
    if (tid < 192) *(float4*)&hs[tid * 4] = a;
    __syncthreads();

    // ---- sharded h_seq write of h[b][tl-1] (plain store, off chain) ----
    if (tl >= 1 && tid >= wgi * 8 && tid < wgi * 8 + 8)
      *(float4*)&h_seq[((size_t)b * S + (tl - 1)) * H + tid * 4] = a;

    // ---- fragments from LDS ----
    float hseg[12];
    *(float4*)&hseg[0] = *(const float4*)&hs[lane * 4];
    *(float4*)&hseg[4] = *(const float4*)&hs[256 + lane * 4];
    *(float4*)&hseg[8] = *(const float4*)&hs[512 + lane * 4];
    __syncthreads();   // hs safe to overwrite next iteration

    float acc[4][3];
#pragma unroll
    for (int c = 0; c < 4; ++c)
#pragma unroll
      for (int gg = 0; gg < 3; ++gg) {
        float s = 0.f;
#pragma unroll
        for (int i = 0; i < 12; ++i) s = fmaf(W[c][gg][i], hseg[i], s);
        acc[c][gg] = s;
      }
#pragma unroll
    for (int c = 0; c < 4; ++c)
#pragma unroll
      for (int gg = 0; gg < 3; ++gg) {
        float v = acc[c][gg];
#pragma unroll
        for (int m = 32; m >= 1; m >>= 1) v += __shfl_xor(v, m);
        acc[c][gg] = v;
      }

    float gi_r = __shfl(gv, (lane & 3));
    float gi_z = __shfl(gv, 4 + (lane & 3));
    float gi_n = __shfl(gv, 8 + (lane & 3));

    if (lane < 4) {
      float ar = acc[0][0], az = acc[0][1], an = acc[0][2];
      if (lane == 1) { ar = acc[1][0]; az = acc[1][1]; an = acc[1][2]; }
      if (lane == 2) { ar = acc[2][0]; az = acc[2][1]; an = acc[2][2]; }
      if (lane == 3) { ar = acc[3][0]; az = acc[3][1]; an = acc[3][2]; }
      float r = 1.f / (1.f + expf(-(gi_r + ar + bh_r)));
      float z = 1.f / (1.f + expf(-(gi_z + az + bh_z)));
      float n = tanhf(gi_n + r * (an + bh_n));
      float hn = (1.f - z) * n + z * h_own;
      h_own = hn;
      // publish: data is its own tag (single one-way coherent store)
      __hip_atomic_store(&hstep[((size_t)tl * 4 + b) * 768 + mycol], hn,
                         __ATOMIC_RELAXED, AGENT);
    }
  }

  // epilogue: write h[b][S-1] to h_seq from registers
  if (lane < 4)
    h_seq[((size_t)b * S + (S - 1)) * H + mycol] = h_own;
}

// ---------------- router + top-2 + gates + expert lists ----------------
__global__ __launch_bounds__(64)
void router_kernel(const float* __restrict__ h_seq, const float* __restrict__ rW,
                   const float* __restrict__ rb, int* __restrict__ counts,
                   int* __restrict__ lists, float* __restrict__ gates)
{
  int t = blockIdx.x;
  int lane = threadIdx.x;
  const float* hp = h_seq + (size_t)t * 768 + lane * 12;
  float h[12];
  *(float4*)&h[0] = *(const float4*)(hp);
  *(float4*)&h[4] = *(const float4*)(hp + 4);
  *(float4*)&h[8] = *(const float4*)(hp + 8);

  float lg[8];
#pragma unroll
  for (int e = 0; e < 8; ++e) {
    const float* wp = rW + e * 768 + lane * 12;
    float s = 0.f;
#pragma unroll
    for (int i = 0; i < 12; ++i) s = fmaf(h[i], wp[i], s);
#pragma unroll
    for (int m = 32; m >= 1; m >>= 1) s += __shfl_xor(s, m);
    lg[e] = s + rb[e];
  }
  if (lane == 0) {
    float v1 = lg[0]; int e1 = 0;
#pragma unroll
    for (int e = 1; e < 8; ++e) {
      if (lg[e] > v1) { v1 = lg[e]; e1 = e; }
    }
    float v2 = -INFINITY; int es = 0;
#pragma unroll
    for (int e = 0; e < 8; ++e) {
      if (e != e1 && lg[e] > v2) { v2 = lg[e]; es = e; }
    }
    float ed = expf(v2 - v1);
    float g1 = 1.f / (1.f + ed);
    float g2 = ed / (1.f + ed);
    int a0 = t * 2, a1 = t * 2 + 1;
    gates[a0] = g1;
    gates[a1] = g2;
    int p = atomicAdd(&counts[e1], 1);
    lists[e1 * 4096 + p] = a0;
    p = atomicAdd(&counts[es], 1);
    lists[es * 4096 + p] = a1;
  }
}

// ---------------- combine: x_next[t] = ybuf[2t] + ybuf[2t+1] ----------------
__global__ __launch_bounds__(256)
void combine_kernel(const float* __restrict__ ybuf, float* __restrict__ out)
{
  int i = blockIdx.x * 256 + threadIdx.x;
  int fi = i * 4;
  int t = fi / 768;
  int d = fi % 768;
  float4 y0 = *(const float4*)&ybuf[(size_t)(2 * t) * 768 + d];
  float4 y1 = *(const float4*)&ybuf[(size_t)(2 * t + 1) * 768 + d];
  float4 r = make_float4(y0.x + y1.x, y0.y + y1.y, y0.z + y1.z, y0.w + y1.w);
  *(float4*)&out[fi] = r;
}

// ---------------- host ----------------
extern "C" void kernel_launch(void* const* d_in, const int* in_sizes, int n_in,
                              void* d_out, int out_size, void* d_ws, size_t ws_size,
                              hipStream_t stream) {
  (void)in_sizes; (void)n_in; (void)out_size; (void)ws_size;
  const float* x      = (const float*)d_in[0];
  const float* proj_W = (const float*)d_in[1];
  const float* proj_b = (const float*)d_in[2];
  const float* Wih    = (const float*)d_in[3];
  const float* Whh    = (const float*)d_in[4];
  const float* bih    = (const float*)d_in[5];
  const float* bhh    = (const float*)d_in[6];
  const float* rW     = (const float*)d_in[7];
  const float* rb     = (const float*)d_in[8];
  const float* eW1    = (const float*)d_in[9];
  const float* eb1    = (const float*)d_in[10];
  const float* eW2    = (const float*)d_in[11];
  const float* eb2    = (const float*)d_in[12];
  float* out = (float*)d_out;

  // workspace layout
  float* f = (float*)d_ws;
  float* h_in  = f;                    // 1,572,864
  float* gi3   = h_in + 1572864;       // 512*4*192*12 = 4,718,592
  float* h_seq = gi3 + 4718592;        // 1,572,864
  float* x_buf = h_seq + 1572864;      // 1,572,864
  float* ybuf  = x_buf + 1572864;      // 3,145,728
  float* hstep = ybuf + 3145728;       // 2*512*4*768 = 3,145,728
  float* zbuf  = hstep + 3145728;      // 3,072 ([4][768] zeros)
  float* gates = zbuf + 3072;          // 4,096
  short* xh    = (short*)(gates + 4096);  // 1,572,864 shorts
  short* xl    = xh + 1572864;            // 1,572,864 shorts
  short* H1h   = xl + 1572864;            // 12,582,912 shorts
  short* H1l   = H1h + 12582912;          // 12,582,912 shorts
  int* ints    = (int*)(H1l + 12582912);
  int* counts  = ints;                 // 16
  int* lists   = ints + 16;            // 8*4096

  reset_kernel<<<3072, 256, 0, stream>>>(hstep, zbuf, counts);

  for (int l = 0; l < 2; ++l) {
    const float* xin = l ? x_buf : x;
    float* hstepL = hstep + (size_t)l * 1572864;
    const float* hprevL = l ? (hstep + (size_t)511 * 3072) : zbuf;

    dim3 g1(6, 16);
    gemm_nt<false><<<g1, 256, 0, stream>>>(
        xin, proj_W + (size_t)l * 768 * 768, proj_b + l * 768, h_in,
        768, 768, 768);

    dim3 g2(18, 16);
    gemm_nt<true><<<g2, 256, 0, stream>>>(
        h_in, Wih, bih, gi3, 768, 768, 0);

    gru_kernel<<<96, 512, 0, stream>>>(gi3, h_seq, hstepL, hprevL, Whh, bhh);

    router_kernel<<<2048, 64, 0, stream>>>(h_seq, rW + (size_t)l * 8 * 768,
                                           rb + l * 8, counts + l * 8, lists, gates);

    split_kernel<<<1536, 256, 0, stream>>>(xin, xh, xl, 393216);

    dim3 ga(24, 32, 8);
    gemm_mfma<true, true, false, true><<<ga, 256, 0, stream>>>(
        xh, xl, eW1 + (size_t)l * 8 * 3072 * 768, eb1 + (size_t)l * 8 * 3072,
        nullptr, H1h, H1l, 768, 768, 3072,
        lists, counts + l * 8, nullptr, (long)3072 * 768, 3072);

    dim3 gb(6, 32, 8);
    gemm_mfma<false, false, true, false><<<gb, 256, 0, stream>>>(
        H1h, H1l, eW2 + (size_t)l * 8 * 768 * 3072, eb2 + (size_t)l * 8 * 768,
        ybuf, nullptr, nullptr, 3072, 3072, 768,
        lists, counts + l * 8, gates, (long)768 * 3072, 768);

    combine_kernel<<<1536, 256, 0, stream>>>(ybuf, l ? out : x_buf);
  }
}